// Round 23
// baseline (84.459 us; speedup 1.0000x reference)
//
#include <hip/hip_runtime.h>

// AttentionCore64: B=2,H=16,S=2048,D=64, fp32 in/out, softmax(QK^T)V, NO 1/sqrt(d).
// R23: R20 verbatim (best 61.97us) with __launch_bounds__(256) — the (256,2)
// clamp pinned VGPR_Count to exactly 128 (the cap). Grid=512 pins 2 blocks/CU
// = 2 waves/SIMD regardless, and 2 x 256 VGPR <= 512/SIMD, so the clamp buys
// nothing; a capped allocator emits remat/copy VALU (suspected source of the
// measured ~2.5x VALU inflation) and loses scheduling freedom.

#define LOG2E 1.44269504088896340736f

typedef _Float16 half8 __attribute__((ext_vector_type(8)));
typedef _Float16 half2v __attribute__((ext_vector_type(2)));
typedef __fp16 fp16x2 __attribute__((ext_vector_type(2)));   // cvt_pkrtz return
typedef float f32x16 __attribute__((ext_vector_type(16)));

#define BH   32
#define SEQ  2048
#define DIM  64
#define QBLK 128             // 2 q-waves x 64 rows
#define KVB  32              // kv rows per parity tile
#define NIT  (SEQ / (2 * KVB))   // 32 tiles, processed 2 per region

union SMem {
  struct { _Float16 K[4][2][KVB * DIM]; _Float16 Vt[4][2][DIM * KVB]; } s;  // 64 KB
  struct { float ob[2][2][2][16 * 64]; float ml[2][2][2][64]; } c;          // 36 KB
};

static __device__ __forceinline__ unsigned pk2(float a, float b) {
  fp16x2 h = __builtin_amdgcn_cvt_pkrtz(a, b);
  return __builtin_bit_cast(unsigned, h);
}

// a' = {a.lo_lanes, b.lo_lanes}; b' = {a.hi_lanes, b.hi_lanes}  (proven R13,
// distinct inputs only)
static __device__ __forceinline__ void plswap(unsigned& a, unsigned& b) {
  asm volatile("v_permlane32_swap_b32 %0, %1" : "+v"(a), "+v"(b));
}

static __device__ __forceinline__ float xmax32(float x) {
  return fmaxf(x, __shfl_xor(x, 32));    // proven through R20
}
static __device__ __forceinline__ float xsum32(float x) {
  return x + __shfl_xor(x, 32);
}

// packed f16 dot: acc += a.h0 + a.h1 (b = {1,1}), f32 accumulate
static __device__ __forceinline__ float dot2(unsigned a, float acc) {
  const half2v ones = {(_Float16)1.0f, (_Float16)1.0f};
  return __builtin_amdgcn_fdot2(__builtin_bit_cast(half2v, a), ones, acc, false);
}

__launch_bounds__(256)
__global__ void attn_fwd(const float* __restrict__ Q, const float* __restrict__ K,
                         const float* __restrict__ V, float* __restrict__ O) {
  __shared__ __align__(16) SMem sm;

  const int tid  = threadIdx.x;
  const int lane = tid & 63;
  const int wave = tid >> 6;
  const int wq   = wave & 1;    // q sub-tile (64 rows)
  const int wk   = wave >> 1;   // kv parity
  const int hi   = lane >> 5;
  const int lq   = lane & 31;

  // XCD swizzle: 512 = 8 xcd * 64; all 16 q-tiles of a bh on one XCD.
  const int bid  = blockIdx.x;
  const int xcd  = bid & 7;
  const int slot = bid >> 3;               // 0..63
  const int bh   = xcd + 8 * (slot >> 4);  // 0..31
  const int qt   = slot & 15;              // 0..15

  const size_t base = (size_t)bh * SEQ * DIM;
  const int qr0 = qt * QBLK + wq * 64 + lq;   // set A row; set B = +32
  const float* qpA = Q + base + (size_t)qr0 * DIM;
  const float* qpB = qpA + 32 * DIM;

  // Q fragments (B-operand of S^T = K*Q^T): lane holds Q[q][d=16c+8hi+j]
  half8 qfA[4], qfB[4];
#pragma unroll
  for (int c = 0; c < 4; ++c) {
    float4 a0 = *(const float4*)(qpA + 16 * c + 8 * hi);
    float4 a1 = *(const float4*)(qpA + 16 * c + 8 * hi + 4);
    union { unsigned u[4]; half8 v; } h;
    h.u[0] = pk2(a0.x, a0.y); h.u[1] = pk2(a0.z, a0.w);
    h.u[2] = pk2(a1.x, a1.y); h.u[3] = pk2(a1.z, a1.w);
    qfA[c] = h.v;
    float4 b0 = *(const float4*)(qpB + 16 * c + 8 * hi);
    float4 b1 = *(const float4*)(qpB + 16 * c + 8 * hi + 4);
    h.u[0] = pk2(b0.x, b0.y); h.u[1] = pk2(b0.z, b0.w);
    h.u[2] = pk2(b1.x, b1.y); h.u[3] = pk2(b1.z, b1.w);
    qfB[c] = h.v;
  }

  f32x16 oA0 = {}, oA1 = {}, oB0 = {}, oB1 = {};   // O^T: d=(r&3)+8*(r>>2)+4hi (+32), q=lq
  float mA = -1e30f, lA = 0.f, mB = -1e30f, lB = 0.f;   // l: lane-local partial

  // ---- prefetch regs: one tile (both parities) of K and V ----
  float4 kreg[2][2];
  float  vreg[2][8];
  const int kr  = tid >> 3;          // K row (0..31)
  const int kd  = (tid & 7) * 8;     // K d-offset
  const int vd  = tid & 63;          // V^T row (d)
  const int vk0 = (tid >> 6) * 8;    // V^T k-offset
  const float* kbp = K + base;
  const float* vbp = V + base;

  auto LOADT = [&](int it) {
#pragma unroll
    for (int p = 0; p < 2; ++p) {
      const int t = 2 * it + p;
      const float* kp = kbp + (size_t)(t * KVB + kr) * DIM + kd;
      kreg[p][0] = *(const float4*)(kp);
      kreg[p][1] = *(const float4*)(kp + 4);
      const float* vp = vbp + (size_t)(t * KVB + vk0) * DIM + vd;
#pragma unroll
      for (int j = 0; j < 8; ++j) vreg[p][j] = vp[j * DIM];
    }
  };

  auto STORET = [&](int b) {
#pragma unroll
    for (int p = 0; p < 2; ++p) {
      union { unsigned u[4]; half8 v; } h;
      h.u[0] = pk2(kreg[p][0].x, kreg[p][0].y);
      h.u[1] = pk2(kreg[p][0].z, kreg[p][0].w);
      h.u[2] = pk2(kreg[p][1].x, kreg[p][1].y);
      h.u[3] = pk2(kreg[p][1].z, kreg[p][1].w);
      const int idx = (kr * DIM + kd) ^ ((kr & 7) << 3);
      *(half8*)&sm.s.K[b][p][idx] = h.v;
      union { unsigned u[4]; half8 v; } g;
      g.u[0] = pk2(vreg[p][0], vreg[p][1]);
      g.u[1] = pk2(vreg[p][2], vreg[p][3]);
      g.u[2] = pk2(vreg[p][4], vreg[p][5]);
      g.u[3] = pk2(vreg[p][6], vreg[p][7]);
      const int vidx = (vd * KVB + vk0) ^ ((vd & 7) << 3);
      *(half8*)&sm.s.Vt[b][p][vidx] = g.v;
    }
  };

  // QK^T of tile in buffer b -> score regs
  auto QKT = [&](int b, f32x16& sA, f32x16& sB) {
    const _Float16* Kt = sm.s.K[b][wk];
    const int ksw = (lq & 7) << 3;
    sA = {}; sB = {};
#pragma unroll
    for (int c = 0; c < 4; ++c) {
      half8 a = *(const half8*)&Kt[(lq * DIM + c * 16 + hi * 8) ^ ksw];
      sA = __builtin_amdgcn_mfma_f32_32x32x16_f16(a, qfA[c], sA, 0, 0, 0);
      sB = __builtin_amdgcn_mfma_f32_32x32x16_f16(a, qfB[c], sB, 0, 0, 0);
    }
  };

  // softmax for one fragment set; emits PV B-fragments pv0 (k0..15), pv1 (k16..31)
  auto softmax_set = [&](const f32x16& s, float& m, float& l,
                         f32x16& o0, f32x16& o1, half8& pv0, half8& pv1) {
    float t0 = fmaxf(fmaxf(s[0],  s[1]),  s[2]);
    float t1 = fmaxf(fmaxf(s[3],  s[4]),  s[5]);
    float t2 = fmaxf(fmaxf(s[6],  s[7]),  s[8]);
    float t3 = fmaxf(fmaxf(s[9],  s[10]), s[11]);
    float t4 = fmaxf(fmaxf(s[12], s[13]), s[14]);
    float t5 = fmaxf(fmaxf(t0, t1), t2);
    float t6 = fmaxf(fmaxf(t3, t4), s[15]);
    float t  = xmax32(fmaxf(t5, t6));     // cross-half max (proven shfl path)
    if (__any(t > m + 10.f)) {            // defer-max THR=10 (p <= e^10 ~ 22k, f16-safe)
      const float mn = fmaxf(m, t);
      const float corr = __builtin_amdgcn_exp2f((m - mn) * LOG2E);
      m = mn; l *= corr;
#pragma unroll
      for (int i = 0; i < 16; ++i) { o0[i] *= corr; o1[i] *= corr; }
    }
    const float nml2 = -m * LOG2E;
    float p[16];
#pragma unroll
    for (int i = 0; i < 16; ++i)
      p[i] = __builtin_amdgcn_exp2f(__builtin_fmaf(s[i], LOG2E, nml2));

    unsigned w[8];
#pragma unroll
    for (int i = 0; i < 8; ++i) w[i] = pk2(p[2 * i], p[2 * i + 1]);

    float la = dot2(w[0], 0.f), lb2 = dot2(w[1], 0.f);
    la = dot2(w[2], la); lb2 = dot2(w[3], lb2);
    la = dot2(w[4], la); lb2 = dot2(w[5], lb2);
    la = dot2(w[6], la); lb2 = dot2(w[7], lb2);
    l += la + lb2;                        // lane-local; cross-half folded at end

    plswap(w[0], w[2]); plswap(w[1], w[3]);
    plswap(w[4], w[6]); plswap(w[5], w[7]);
    union { unsigned u[4]; half8 v; } f;
    f.u[0] = w[0]; f.u[1] = w[1]; f.u[2] = w[2]; f.u[3] = w[3];
    pv0 = f.v;
    f.u[0] = w[4]; f.u[1] = w[5]; f.u[2] = w[6]; f.u[3] = w[7];
    pv1 = f.v;
  };

  // PV accumulate from Vt buffer b
  auto PVT = [&](int b, const half8& pA0, const half8& pA1,
                 const half8& pB0, const half8& pB1) {
    const _Float16* Vt = sm.s.Vt[b][wk];
    const int d0 = lq, d1 = 32 + lq;
    const int sz0 = (d0 & 7) << 3, sz1 = (d1 & 7) << 3;
    {
      half8 a = *(const half8*)&Vt[(d0 * KVB + 0 + hi * 8) ^ sz0];
      oA0 = __builtin_amdgcn_mfma_f32_32x32x16_f16(a, pA0, oA0, 0, 0, 0);
      oB0 = __builtin_amdgcn_mfma_f32_32x32x16_f16(a, pB0, oB0, 0, 0, 0);
    }
    {
      half8 a = *(const half8*)&Vt[(d1 * KVB + 0 + hi * 8) ^ sz1];
      oA1 = __builtin_amdgcn_mfma_f32_32x32x16_f16(a, pA0, oA1, 0, 0, 0);
      oB1 = __builtin_amdgcn_mfma_f32_32x32x16_f16(a, pB0, oB1, 0, 0, 0);
    }
    {
      half8 a = *(const half8*)&Vt[(d0 * KVB + 16 + hi * 8) ^ sz0];
      oA0 = __builtin_amdgcn_mfma_f32_32x32x16_f16(a, pA1, oA0, 0, 0, 0);
      oB0 = __builtin_amdgcn_mfma_f32_32x32x16_f16(a, pB1, oB0, 0, 0, 0);
    }
    {
      half8 a = *(const half8*)&Vt[(d1 * KVB + 16 + hi * 8) ^ sz1];
      oA1 = __builtin_amdgcn_mfma_f32_32x32x16_f16(a, pA1, oA1, 0, 0, 0);
      oB1 = __builtin_amdgcn_mfma_f32_32x32x16_f16(a, pB1, oB1, 0, 0, 0);
    }
  };

  // ---- prologue: stage tiles 0,1 into bufs 0,1; regs <- tile 2 ----
  LOADT(0);
  STORET(0);
  LOADT(1);
  STORET(1);            // vmcnt wait on LOADT(1) — prologue only, cheap
  LOADT(2);
  __syncthreads();

  for (int j = 0; j < NIT / 2; ++j) {
    const int t = 2 * j;
    const int bA = t & 3, bB = (t + 1) & 3;

    // stage tile t+2 (regs from last region's LOADT(t+2)); prefetch t+3
    if (t + 2 < NIT) {
      STORET((t + 2) & 3);      // target: last read in region j-1, 1 barrier ago
      LOADT(t + 3);
    }

    // two independent QK chains (16 MFMA) — scores both live
    f32x16 sA0, sB0, sA1, sB1;
    QKT(bA, sA0, sB0);
    QKT(bB, sA1, sB1);

    // chain t: softmax + PV  (VALU here overlaps the QK/PV MFMAs around it)
    half8 pA0, pA1, pB0, pB1;
    softmax_set(sA0, mA, lA, oA0, oA1, pA0, pA1);
    softmax_set(sB0, mB, lB, oB0, oB1, pB0, pB1);
    PVT(bA, pA0, pA1, pB0, pB1);

    // stage tile t+3 (vmcnt on LOADT(t+3) covered by the compute above)
    if (t + 3 < NIT) {
      STORET((t + 3) & 3);
      if (t + 4 < NIT) LOADT(t + 4);
    }

    // chain t+1: softmax + PV
    softmax_set(sA1, mA, lA, oA0, oA1, pA0, pA1);
    softmax_set(sB1, mB, lB, oB0, oB1, pB0, pB1);
    PVT(bB, pA0, pA1, pB0, pB1);

    __syncthreads();            // single barrier per 2 tiles
  }

  // fold cross-half partial sums once (both halves share m -> valid)
  lA = xsum32(lA);
  lB = xsum32(lB);

  // ---- combine kv-parities via LDS (union reuse after staging done) ----
  if (wk == 1) {
#pragma unroll
    for (int r = 0; r < 16; ++r) {
      sm.c.ob[wq][0][0][r * 64 + lane] = oA0[r];
      sm.c.ob[wq][0][1][r * 64 + lane] = oA1[r];
      sm.c.ob[wq][1][0][r * 64 + lane] = oB0[r];
      sm.c.ob[wq][1][1][r * 64 + lane] = oB1[r];
    }
    sm.c.ml[wq][0][0][lane] = mA; sm.c.ml[wq][0][1][lane] = lA;
    sm.c.ml[wq][1][0][lane] = mB; sm.c.ml[wq][1][1][lane] = lB;
  }
  __syncthreads();
  if (wk == 0) {
    auto emit = [&](int set, int qrow, const f32x16& o0, const f32x16& o1,
                    float m, float l) {
      const float mb = sm.c.ml[wq][set][0][lane];
      const float lb = sm.c.ml[wq][set][1][lane];
      const float mx = fmaxf(m, mb);
      const float ca = __builtin_amdgcn_exp2f((m - mx) * LOG2E);
      const float cb = __builtin_amdgcn_exp2f((mb - mx) * LOG2E);
      const float inv = 1.0f / (l * ca + lb * cb);
      float* op = O + base + (size_t)qrow * DIM;
#pragma unroll
      for (int g = 0; g < 4; ++g) {
        float4 r0, r1;
        r0.x = (o0[4*g+0] * ca + sm.c.ob[wq][set][0][(4*g+0)*64 + lane] * cb) * inv;
        r0.y = (o0[4*g+1] * ca + sm.c.ob[wq][set][0][(4*g+1)*64 + lane] * cb) * inv;
        r0.z = (o0[4*g+2] * ca + sm.c.ob[wq][set][0][(4*g+2)*64 + lane] * cb) * inv;
        r0.w = (o0[4*g+3] * ca + sm.c.ob[wq][set][0][(4*g+3)*64 + lane] * cb) * inv;
        r1.x = (o1[4*g+0] * ca + sm.c.ob[wq][set][1][(4*g+0)*64 + lane] * cb) * inv;
        r1.y = (o1[4*g+1] * ca + sm.c.ob[wq][set][1][(4*g+1)*64 + lane] * cb) * inv;
        r1.z = (o1[4*g+2] * ca + sm.c.ob[wq][set][1][(4*g+2)*64 + lane] * cb) * inv;
        r1.w = (o1[4*g+3] * ca + sm.c.ob[wq][set][1][(4*g+3)*64 + lane] * cb) * inv;
        *(float4*)(op + 8 * g + 4 * hi) = r0;        // d = 8g+4hi..+3
        *(float4*)(op + 32 + 8 * g + 4 * hi) = r1;   // d = 32+8g+4hi..+3
      }
    };
    emit(0, qr0,      oA0, oA1, mA, lA);
    emit(1, qr0 + 32, oB0, oB1, mB, lB);
  }
}

extern "C" void kernel_launch(void* const* d_in, const int* in_sizes, int n_in,
                              void* d_out, int out_size, void* d_ws, size_t ws_size,
                              hipStream_t stream) {
  const float* q = (const float*)d_in[0];
  const float* k = (const float*)d_in[1];
  const float* v = (const float*)d_in[2];
  float* o = (float*)d_out;
  attn_fwd<<<BH * (SEQ / QBLK), 256, 0, stream>>>(q, k, v, o);
}

// Round 27
// 61.959 us; speedup vs baseline: 1.3631x; 1.3631x over previous
//
#include <hip/hip_runtime.h>

// AttentionCore64: B=2,H=16,S=2048,D=64, fp32 in/out, softmax(QK^T)V, NO 1/sqrt(d).
// R27: REVERT to R20 verbatim — the session's best verified kernel (61.97us).
// R24/R25/R26 condemned the equal-input permlane32_swap max (4 forms, all fail);
// __shfl_xor is the only verified cross-half reduction. Structure: 2 tiles per
// barrier region, 4 LDS buffers, swapped QK^T, defer-max THR=10, fdot2 denom,
// distinct-input plswap P-exchange, XCD swizzle, grid=512, (256,2).

#define LOG2E 1.44269504088896340736f

typedef _Float16 half8 __attribute__((ext_vector_type(8)));
typedef _Float16 half2v __attribute__((ext_vector_type(2)));
typedef __fp16 fp16x2 __attribute__((ext_vector_type(2)));   // cvt_pkrtz return
typedef float f32x16 __attribute__((ext_vector_type(16)));

#define BH   32
#define SEQ  2048
#define DIM  64
#define QBLK 128             // 2 q-waves x 64 rows
#define KVB  32              // kv rows per parity tile
#define NIT  (SEQ / (2 * KVB))   // 32 tiles, processed 2 per region

union SMem {
  struct { _Float16 K[4][2][KVB * DIM]; _Float16 Vt[4][2][DIM * KVB]; } s;  // 64 KB
  struct { float ob[2][2][2][16 * 64]; float ml[2][2][2][64]; } c;          // 36 KB
};

static __device__ __forceinline__ unsigned pk2(float a, float b) {
  fp16x2 h = __builtin_amdgcn_cvt_pkrtz(a, b);
  return __builtin_bit_cast(unsigned, h);
}

// a' = {a.lo_lanes, b.lo_lanes}; b' = {a.hi_lanes, b.hi_lanes}  (proven R13,
// distinct-value inputs only — equal-input forms are condemned, R17/24/25/26)
static __device__ __forceinline__ void plswap(unsigned& a, unsigned& b) {
  asm volatile("v_permlane32_swap_b32 %0, %1" : "+v"(a), "+v"(b));
}

static __device__ __forceinline__ float xmax32(float x) {
  return fmaxf(x, __shfl_xor(x, 32));    // proven path
}
static __device__ __forceinline__ float xsum32(float x) {
  return x + __shfl_xor(x, 32);
}

// packed f16 dot: acc += a.h0 + a.h1 (b = {1,1}), f32 accumulate
static __device__ __forceinline__ float dot2(unsigned a, float acc) {
  const half2v ones = {(_Float16)1.0f, (_Float16)1.0f};
  return __builtin_amdgcn_fdot2(__builtin_bit_cast(half2v, a), ones, acc, false);
}

__launch_bounds__(256, 2)
__global__ void attn_fwd(const float* __restrict__ Q, const float* __restrict__ K,
                         const float* __restrict__ V, float* __restrict__ O) {
  __shared__ __align__(16) SMem sm;

  const int tid  = threadIdx.x;
  const int lane = tid & 63;
  const int wave = tid >> 6;
  const int wq   = wave & 1;    // q sub-tile (64 rows)
  const int wk   = wave >> 1;   // kv parity
  const int hi   = lane >> 5;
  const int lq   = lane & 31;

  // XCD swizzle: 512 = 8 xcd * 64; all 16 q-tiles of a bh on one XCD.
  const int bid  = blockIdx.x;
  const int xcd  = bid & 7;
  const int slot = bid >> 3;               // 0..63
  const int bh   = xcd + 8 * (slot >> 4);  // 0..31
  const int qt   = slot & 15;              // 0..15

  const size_t base = (size_t)bh * SEQ * DIM;
  const int qr0 = qt * QBLK + wq * 64 + lq;   // set A row; set B = +32
  const float* qpA = Q + base + (size_t)qr0 * DIM;
  const float* qpB = qpA + 32 * DIM;

  // Q fragments (B-operand of S^T = K*Q^T): lane holds Q[q][d=16c+8hi+j]
  half8 qfA[4], qfB[4];
#pragma unroll
  for (int c = 0; c < 4; ++c) {
    float4 a0 = *(const float4*)(qpA + 16 * c + 8 * hi);
    float4 a1 = *(const float4*)(qpA + 16 * c + 8 * hi + 4);
    union { unsigned u[4]; half8 v; } h;
    h.u[0] = pk2(a0.x, a0.y); h.u[1] = pk2(a0.z, a0.w);
    h.u[2] = pk2(a1.x, a1.y); h.u[3] = pk2(a1.z, a1.w);
    qfA[c] = h.v;
    float4 b0 = *(const float4*)(qpB + 16 * c + 8 * hi);
    float4 b1 = *(const float4*)(qpB + 16 * c + 8 * hi + 4);
    h.u[0] = pk2(b0.x, b0.y); h.u[1] = pk2(b0.z, b0.w);
    h.u[2] = pk2(b1.x, b1.y); h.u[3] = pk2(b1.z, b1.w);
    qfB[c] = h.v;
  }

  f32x16 oA0 = {}, oA1 = {}, oB0 = {}, oB1 = {};   // O^T: d=(r&3)+8*(r>>2)+4hi (+32), q=lq
  float mA = -1e30f, lA = 0.f, mB = -1e30f, lB = 0.f;   // l: lane-local partial

  // ---- prefetch regs: one tile (both parities) of K and V ----
  float4 kreg[2][2];
  float  vreg[2][8];
  const int kr  = tid >> 3;          // K row (0..31)
  const int kd  = (tid & 7) * 8;     // K d-offset
  const int vd  = tid & 63;          // V^T row (d)
  const int vk0 = (tid >> 6) * 8;    // V^T k-offset
  const float* kbp = K + base;
  const float* vbp = V + base;

  auto LOADT = [&](int it) {
#pragma unroll
    for (int p = 0; p < 2; ++p) {
      const int t = 2 * it + p;
      const float* kp = kbp + (size_t)(t * KVB + kr) * DIM + kd;
      kreg[p][0] = *(const float4*)(kp);
      kreg[p][1] = *(const float4*)(kp + 4);
      const float* vp = vbp + (size_t)(t * KVB + vk0) * DIM + vd;
#pragma unroll
      for (int j = 0; j < 8; ++j) vreg[p][j] = vp[j * DIM];
    }
  };

  auto STORET = [&](int b) {
#pragma unroll
    for (int p = 0; p < 2; ++p) {
      union { unsigned u[4]; half8 v; } h;
      h.u[0] = pk2(kreg[p][0].x, kreg[p][0].y);
      h.u[1] = pk2(kreg[p][0].z, kreg[p][0].w);
      h.u[2] = pk2(kreg[p][1].x, kreg[p][1].y);
      h.u[3] = pk2(kreg[p][1].z, kreg[p][1].w);
      const int idx = (kr * DIM + kd) ^ ((kr & 7) << 3);
      *(half8*)&sm.s.K[b][p][idx] = h.v;
      union { unsigned u[4]; half8 v; } g;
      g.u[0] = pk2(vreg[p][0], vreg[p][1]);
      g.u[1] = pk2(vreg[p][2], vreg[p][3]);
      g.u[2] = pk2(vreg[p][4], vreg[p][5]);
      g.u[3] = pk2(vreg[p][6], vreg[p][7]);
      const int vidx = (vd * KVB + vk0) ^ ((vd & 7) << 3);
      *(half8*)&sm.s.Vt[b][p][vidx] = g.v;
    }
  };

  // QK^T of tile in buffer b -> score regs
  auto QKT = [&](int b, f32x16& sA, f32x16& sB) {
    const _Float16* Kt = sm.s.K[b][wk];
    const int ksw = (lq & 7) << 3;
    sA = {}; sB = {};
#pragma unroll
    for (int c = 0; c < 4; ++c) {
      half8 a = *(const half8*)&Kt[(lq * DIM + c * 16 + hi * 8) ^ ksw];
      sA = __builtin_amdgcn_mfma_f32_32x32x16_f16(a, qfA[c], sA, 0, 0, 0);
      sB = __builtin_amdgcn_mfma_f32_32x32x16_f16(a, qfB[c], sB, 0, 0, 0);
    }
  };

  // softmax for one fragment set; emits PV B-fragments pv0 (k0..15), pv1 (k16..31)
  auto softmax_set = [&](const f32x16& s, float& m, float& l,
                         f32x16& o0, f32x16& o1, half8& pv0, half8& pv1) {
    float t0 = fmaxf(fmaxf(s[0],  s[1]),  s[2]);
    float t1 = fmaxf(fmaxf(s[3],  s[4]),  s[5]);
    float t2 = fmaxf(fmaxf(s[6],  s[7]),  s[8]);
    float t3 = fmaxf(fmaxf(s[9],  s[10]), s[11]);
    float t4 = fmaxf(fmaxf(s[12], s[13]), s[14]);
    float t5 = fmaxf(fmaxf(t0, t1), t2);
    float t6 = fmaxf(fmaxf(t3, t4), s[15]);
    float t  = xmax32(fmaxf(t5, t6));     // cross-half max (proven shfl path)
    if (__any(t > m + 10.f)) {            // defer-max THR=10 (p <= e^10 ~ 22k, f16-safe)
      const float mn = fmaxf(m, t);
      const float corr = __builtin_amdgcn_exp2f((m - mn) * LOG2E);
      m = mn; l *= corr;
#pragma unroll
      for (int i = 0; i < 16; ++i) { o0[i] *= corr; o1[i] *= corr; }
    }
    const float nml2 = -m * LOG2E;
    float p[16];
#pragma unroll
    for (int i = 0; i < 16; ++i)
      p[i] = __builtin_amdgcn_exp2f(__builtin_fmaf(s[i], LOG2E, nml2));

    unsigned w[8];
#pragma unroll
    for (int i = 0; i < 8; ++i) w[i] = pk2(p[2 * i], p[2 * i + 1]);

    float la = dot2(w[0], 0.f), lb2 = dot2(w[1], 0.f);
    la = dot2(w[2], la); lb2 = dot2(w[3], lb2);
    la = dot2(w[4], la); lb2 = dot2(w[5], lb2);
    la = dot2(w[6], la); lb2 = dot2(w[7], lb2);
    l += la + lb2;                        // lane-local; cross-half folded at end

    plswap(w[0], w[2]); plswap(w[1], w[3]);
    plswap(w[4], w[6]); plswap(w[5], w[7]);
    union { unsigned u[4]; half8 v; } f;
    f.u[0] = w[0]; f.u[1] = w[1]; f.u[2] = w[2]; f.u[3] = w[3];
    pv0 = f.v;
    f.u[0] = w[4]; f.u[1] = w[5]; f.u[2] = w[6]; f.u[3] = w[7];
    pv1 = f.v;
  };

  // PV accumulate from Vt buffer b
  auto PVT = [&](int b, const half8& pA0, const half8& pA1,
                 const half8& pB0, const half8& pB1) {
    const _Float16* Vt = sm.s.Vt[b][wk];
    const int d0 = lq, d1 = 32 + lq;
    const int sz0 = (d0 & 7) << 3, sz1 = (d1 & 7) << 3;
    {
      half8 a = *(const half8*)&Vt[(d0 * KVB + 0 + hi * 8) ^ sz0];
      oA0 = __builtin_amdgcn_mfma_f32_32x32x16_f16(a, pA0, oA0, 0, 0, 0);
      oB0 = __builtin_amdgcn_mfma_f32_32x32x16_f16(a, pB0, oB0, 0, 0, 0);
    }
    {
      half8 a = *(const half8*)&Vt[(d1 * KVB + 0 + hi * 8) ^ sz1];
      oA1 = __builtin_amdgcn_mfma_f32_32x32x16_f16(a, pA0, oA1, 0, 0, 0);
      oB1 = __builtin_amdgcn_mfma_f32_32x32x16_f16(a, pB0, oB1, 0, 0, 0);
    }
    {
      half8 a = *(const half8*)&Vt[(d0 * KVB + 16 + hi * 8) ^ sz0];
      oA0 = __builtin_amdgcn_mfma_f32_32x32x16_f16(a, pA1, oA0, 0, 0, 0);
      oB0 = __builtin_amdgcn_mfma_f32_32x32x16_f16(a, pB1, oB0, 0, 0, 0);
    }
    {
      half8 a = *(const half8*)&Vt[(d1 * KVB + 16 + hi * 8) ^ sz1];
      oA1 = __builtin_amdgcn_mfma_f32_32x32x16_f16(a, pA1, oA1, 0, 0, 0);
      oB1 = __builtin_amdgcn_mfma_f32_32x32x16_f16(a, pB1, oB1, 0, 0, 0);
    }
  };

  // ---- prologue: stage tiles 0,1 into bufs 0,1; regs <- tile 2 ----
  LOADT(0);
  STORET(0);
  LOADT(1);
  STORET(1);            // vmcnt wait on LOADT(1) — prologue only, cheap
  LOADT(2);
  __syncthreads();

  for (int j = 0; j < NIT / 2; ++j) {
    const int t = 2 * j;
    const int bA = t & 3, bB = (t + 1) & 3;

    // stage tile t+2 (regs from last region's LOADT(t+2)); prefetch t+3
    if (t + 2 < NIT) {
      STORET((t + 2) & 3);      // target: last read in region j-1, 1 barrier ago
      LOADT(t + 3);
    }

    // two independent QK chains (16 MFMA) — scores both live
    f32x16 sA0, sB0, sA1, sB1;
    QKT(bA, sA0, sB0);
    QKT(bB, sA1, sB1);

    // chain t: softmax + PV  (VALU here overlaps the QK/PV MFMAs around it)
    half8 pA0, pA1, pB0, pB1;
    softmax_set(sA0, mA, lA, oA0, oA1, pA0, pA1);
    softmax_set(sB0, mB, lB, oB0, oB1, pB0, pB1);
    PVT(bA, pA0, pA1, pB0, pB1);

    // stage tile t+3 (vmcnt on LOADT(t+3) covered by the compute above)
    if (t + 3 < NIT) {
      STORET((t + 3) & 3);
      if (t + 4 < NIT) LOADT(t + 4);
    }

    // chain t+1: softmax + PV
    softmax_set(sA1, mA, lA, oA0, oA1, pA0, pA1);
    softmax_set(sB1, mB, lB, oB0, oB1, pB0, pB1);
    PVT(bB, pA0, pA1, pB0, pB1);

    __syncthreads();            // single barrier per 2 tiles
  }

  // fold cross-half partial sums once (both halves share m -> valid)
  lA = xsum32(lA);
  lB = xsum32(lB);

  // ---- combine kv-parities via LDS (union reuse after staging done) ----
  if (wk == 1) {
#pragma unroll
    for (int r = 0; r < 16; ++r) {
      sm.c.ob[wq][0][0][r * 64 + lane] = oA0[r];
      sm.c.ob[wq][0][1][r * 64 + lane] = oA1[r];
      sm.c.ob[wq][1][0][r * 64 + lane] = oB0[r];
      sm.c.ob[wq][1][1][r * 64 + lane] = oB1[r];
    }
    sm.c.ml[wq][0][0][lane] = mA; sm.c.ml[wq][0][1][lane] = lA;
    sm.c.ml[wq][1][0][lane] = mB; sm.c.ml[wq][1][1][lane] = lB;
  }
  __syncthreads();
  if (wk == 0) {
    auto emit = [&](int set, int qrow, const f32x16& o0, const f32x16& o1,
                    float m, float l) {
      const float mb = sm.c.ml[wq][set][0][lane];
      const float lb = sm.c.ml[wq][set][1][lane];
      const float mx = fmaxf(m, mb);
      const float ca = __builtin_amdgcn_exp2f((m - mx) * LOG2E);
      const float cb = __builtin_amdgcn_exp2f((mb - mx) * LOG2E);
      const float inv = 1.0f / (l * ca + lb * cb);
      float* op = O + base + (size_t)qrow * DIM;
#pragma unroll
      for (int g = 0; g < 4; ++g) {
        float4 r0, r1;
        r0.x = (o0[4*g+0] * ca + sm.c.ob[wq][set][0][(4*g+0)*64 + lane] * cb) * inv;
        r0.y = (o0[4*g+1] * ca + sm.c.ob[wq][set][0][(4*g+1)*64 + lane] * cb) * inv;
        r0.z = (o0[4*g+2] * ca + sm.c.ob[wq][set][0][(4*g+2)*64 + lane] * cb) * inv;
        r0.w = (o0[4*g+3] * ca + sm.c.ob[wq][set][0][(4*g+3)*64 + lane] * cb) * inv;
        r1.x = (o1[4*g+0] * ca + sm.c.ob[wq][set][1][(4*g+0)*64 + lane] * cb) * inv;
        r1.y = (o1[4*g+1] * ca + sm.c.ob[wq][set][1][(4*g+1)*64 + lane] * cb) * inv;
        r1.z = (o1[4*g+2] * ca + sm.c.ob[wq][set][1][(4*g+2)*64 + lane] * cb) * inv;
        r1.w = (o1[4*g+3] * ca + sm.c.ob[wq][set][1][(4*g+3)*64 + lane] * cb) * inv;
        *(float4*)(op + 8 * g + 4 * hi) = r0;        // d = 8g+4hi..+3
        *(float4*)(op + 32 + 8 * g + 4 * hi) = r1;   // d = 32+8g+4hi..+3
      }
    };
    emit(0, qr0,      oA0, oA1, mA, lA);
    emit(1, qr0 + 32, oB0, oB1, mB, lB);
  }
}

extern "C" void kernel_launch(void* const* d_in, const int* in_sizes, int n_in,
                              void* d_out, int out_size, void* d_ws, size_t ws_size,
                              hipStream_t stream) {
  const float* q = (const float*)d_in[0];
  const float* k = (const float*)d_in[1];
  const float* v = (const float*)d_in[2];
  float* o = (float*)d_out;
  attn_fwd<<<BH * (SEQ / QBLK), 256, 0, stream>>>(q, k, v, o);
}